// Round 16
// baseline (360.289 us; speedup 1.0000x reference)
//
#include <hip/hip_runtime.h>
#include <hip/hip_bf16.h>
#include <cstdint>
#include <cstddef>

// GCN restructured:
//   conv1: agg RAW 3-dim features, W1 AFTER agg.  conv2: agg bf16 h1s rows -> bf16 g2s,
//   then MFMA bf16 GEMM (g2s @ W2) with relu+Wf+pool fused; block partials + LDS-staged W2T.
// k_deg/k_fill dst-WINDOWED (8 windows via blockIdx&7) for XCD-L2-local atomics.
// NEW: nontemporal loads on all single-use int streams (dst/src/csr) so L2 keeps the
// hot scatter/gather lines instead of stream data (write-amp was 11x ideal).

#define HID 128
#define NWIN 8

typedef short bf16x8 __attribute__((ext_vector_type(8)));
typedef float f32x4 __attribute__((ext_vector_type(4)));

__device__ inline float bflo(unsigned u) { return __uint_as_float(u << 16); }
__device__ inline float bfhi(unsigned u) { return __uint_as_float(u & 0xffff0000u); }
__device__ inline unsigned short f2bf(float f) {
    __hip_bfloat16 q = __float2bfloat16(f);
    return *(unsigned short*)&q;
}
__device__ inline int ntload(const int* p) { return __builtin_nontemporal_load(p); }

// windowed degree count: window = blockIdx&7; deg atomics stay in one XCD's L2.
__global__ __launch_bounds__(256) void k_deg(const int* __restrict__ dst,
                                             int* __restrict__ deg,
                                             int* __restrict__ wintot, int E, int nper) {
    __shared__ int sb[4];
    int win = blockIdx.x & (NWIN - 1);
    int nblk = gridDim.x >> 3;
    int bw = blockIdx.x >> 3;
    int lo = win * nper, hi = lo + nper;
    int cnt = 0;
    for (int e = bw * 256 + threadIdx.x; e < E; e += nblk * 256) {
        int d = ntload(&dst[e]);
        if (d >= lo && d < hi) {
            atomicAdd(&deg[d], 1);
            ++cnt;
        }
    }
    #pragma unroll
    for (int o = 32; o > 0; o >>= 1) cnt += __shfl_down(cnt, o);
    int wv = threadIdx.x >> 6;
    if ((threadIdx.x & 63) == 0) sb[wv] = cnt;
    __syncthreads();
    if (threadIdx.x == 0) atomicAdd(&wintot[win], sb[0] + sb[1] + sb[2] + sb[3]);
}

__global__ void k_winscan(const int* __restrict__ wintot, int* __restrict__ wincur) {
    int t = threadIdx.x;
    int v = (t < NWIN) ? wintot[t] : 0;
    int p = v;
    #pragma unroll
    for (int o = 1; o < NWIN; o <<= 1) {
        int u = __shfl_up(p, o);
        if (t >= o) p += u;
    }
    if (t < NWIN) wincur[t] = p - v;
}

// W2T[c][k] = bf16(W2[k][c])  (32KB, built once, L2-resident)
__global__ void k_w2t(const float* __restrict__ W2, unsigned short* __restrict__ W2T) {
    int i = blockIdx.x * 256 + threadIdx.x;
    if (i < HID * HID) {
        int k = i >> 7, c = i & 127;
        W2T[c * HID + k] = f2bf(W2[k * HID + c]);
    }
}

// node range start within its window (order-free, one atomic per wave);
// also dinv[i] and xs[i] = {x*dinv, dinv}.
__global__ void k_off(const int* __restrict__ deg, const float* __restrict__ x,
                      int* __restrict__ off, int* __restrict__ cursor,
                      float* __restrict__ dinv, float4* __restrict__ xs,
                      int* __restrict__ wincur, int n, int nper) {
    int i = blockIdx.x * 256 + threadIdx.x;
    int lane = threadIdx.x & 63;
    int d = (i < n) ? deg[i] : 0;
    int win = (i < n) ? (i / nper) : (NWIN - 1);
    int p = d;
    #pragma unroll
    for (int o = 1; o < 64; o <<= 1) {
        int v = __shfl_up(p, o);
        if (lane >= o) p += v;
    }
    int base = 0;
    if (lane == 63) base = atomicAdd(&wincur[win], p);
    base = __shfl(base, 63);
    int my = base + p - d;
    if (i < n) {
        off[i] = my; cursor[i] = my;
        float di = rsqrtf((float)(d + 1));
        dinv[i] = di;
        xs[i] = make_float4(x[i * 3 + 0] * di, x[i * 3 + 1] * di, x[i * 3 + 2] * di, di);
    }
}

// windowed CSR fill (NT loads on both edge streams; csr store stays cached)
__global__ __launch_bounds__(256) void k_fill(const int* __restrict__ src,
                                              const int* __restrict__ dst,
                                              int* __restrict__ cursor,
                                              int* __restrict__ csr, int E, int nper) {
    int win = blockIdx.x & (NWIN - 1);
    int nblk = gridDim.x >> 3;
    int bw = blockIdx.x >> 3;
    int lo = win * nper, hi = lo + nper;
    for (int e = bw * 256 + threadIdx.x; e < E; e += nblk * 256) {
        int d = ntload(&dst[e]);
        if (d >= lo && d < hi) {
            int p = atomicAdd(&cursor[d], 1);
            csr[p] = ntload(&src[e]);
        }
    }
}

// conv1 aggregation on 3-dim raw features: one THREAD per node, 4x unrolled.
// csr is a single-use stream -> NT; xs is reused -> cached.
__global__ void k_agg1(const float4* __restrict__ xs, const int* __restrict__ off,
                       const int* __restrict__ deg, const int* __restrict__ csr,
                       float4* __restrict__ agg1, int n) {
    int i = blockIdx.x * 256 + threadIdx.x;
    if (i >= n) return;
    int e0 = off[i], e1 = e0 + deg[i];
    float sx = 0.f, sy = 0.f, sz = 0.f;
    int e = e0;
    for (; e + 4 <= e1; e += 4) {
        int s0 = ntload(&csr[e]), s1 = ntload(&csr[e + 1]);
        int s2 = ntload(&csr[e + 2]), s3 = ntload(&csr[e + 3]);
        float4 v0 = xs[s0], v1 = xs[s1], v2 = xs[s2], v3 = xs[s3];
        sx += v0.x + v1.x + v2.x + v3.x;
        sy += v0.y + v1.y + v2.y + v3.y;
        sz += v0.z + v1.z + v2.z + v3.z;
    }
    for (; e < e1; ++e) {
        float4 v = xs[ntload(&csr[e])];
        sx += v.x; sy += v.y; sz += v.z;
    }
    float4 self = xs[i];
    float di = self.w;
    agg1[i] = make_float4((sx + self.x) * di, (sy + self.y) * di, (sz + self.z) * di, di);
}

// h1s[i] = bf16( relu(agg1[i].xyz @ W1 + b1) * dinv )
__global__ __launch_bounds__(256) void k_h1(const float4* __restrict__ agg1,
                                            const float* __restrict__ W1,
                                            const float* __restrict__ b1,
                                            unsigned short* __restrict__ h1s, int n) {
    int wv = threadIdx.x >> 6;
    int lane = threadIdx.x & 63;
    int i = blockIdx.x * 4 + wv;
    if (i >= n) return;
    int c0 = lane * 2;
    float4 a = agg1[i];
    float h0 = fmaxf(a.x * W1[0 * HID + c0]     + a.y * W1[1 * HID + c0]     + a.z * W1[2 * HID + c0]     + b1[c0],     0.f) * a.w;
    float h1 = fmaxf(a.x * W1[0 * HID + c0 + 1] + a.y * W1[1 * HID + c0 + 1] + a.z * W1[2 * HID + c0 + 1] + b1[c0 + 1], 0.f) * a.w;
    ushort2 pk;
    pk.x = f2bf(h0);
    pk.y = f2bf(h1);
    *(ushort2*)&h1s[(size_t)i * HID + c0] = pk;
}

// conv2 aggregation over bf16 rows; csr NT-streamed, h1s gathers cached.
__global__ __launch_bounds__(256) void k_agg2(const unsigned short* __restrict__ h1s,
                                              const float* __restrict__ dinv,
                                              const int* __restrict__ off,
                                              const int* __restrict__ deg,
                                              const int* __restrict__ csr,
                                              unsigned short* __restrict__ g2s, int n) {
    int wv = threadIdx.x >> 6;
    int lane = threadIdx.x & 63;
    int half = lane >> 5;
    int col = lane & 31;
    int node = blockIdx.x * 4 + wv;
    if (node >= n) return;
    int e0 = off[node], e1 = e0 + deg[node];
    float ax = 0.f, ay = 0.f, az = 0.f, aw = 0.f;

    for (int base = e0; base < e1; base += 64) {
        int m = e1 - base; if (m > 64) m = 64;
        int idx = (base + lane < e1) ? ntload(&csr[base + lane]) : 0;
        int j = 0;
        for (; j + 8 <= m; j += 8) {
            int s0 = __shfl(idx, j + 0 + half);
            int s1 = __shfl(idx, j + 2 + half);
            int s2 = __shfl(idx, j + 4 + half);
            int s3 = __shfl(idx, j + 6 + half);
            uint2 r0 = *(const uint2*)&h1s[(size_t)s0 * HID + col * 4];
            uint2 r1 = *(const uint2*)&h1s[(size_t)s1 * HID + col * 4];
            uint2 r2 = *(const uint2*)&h1s[(size_t)s2 * HID + col * 4];
            uint2 r3 = *(const uint2*)&h1s[(size_t)s3 * HID + col * 4];
            ax += bflo(r0.x) + bflo(r1.x) + bflo(r2.x) + bflo(r3.x);
            ay += bfhi(r0.x) + bfhi(r1.x) + bfhi(r2.x) + bfhi(r3.x);
            az += bflo(r0.y) + bflo(r1.y) + bflo(r2.y) + bflo(r3.y);
            aw += bfhi(r0.y) + bfhi(r1.y) + bfhi(r2.y) + bfhi(r3.y);
        }
        for (; j < m; j += 2) {
            int jj = j + half;
            if (jj < m) {
                int s = __shfl(idx, jj);
                uint2 r = *(const uint2*)&h1s[(size_t)s * HID + col * 4];
                ax += bflo(r.x); ay += bfhi(r.x);
                az += bflo(r.y); aw += bfhi(r.y);
            }
        }
    }
    ax += __shfl_down(ax, 32);
    ay += __shfl_down(ay, 32);
    az += __shfl_down(az, 32);
    aw += __shfl_down(aw, 32);

    if (half == 0) {
        uint2 r = *(const uint2*)&h1s[(size_t)node * HID + col * 4];
        float di = dinv[node];
        ushort4 pk;
        pk.x = f2bf((ax + bflo(r.x)) * di);
        pk.y = f2bf((ay + bfhi(r.x)) * di);
        pk.z = f2bf((az + bflo(r.y)) * di);
        pk.w = f2bf((aw + bfhi(r.y)) * di);
        *(ushort4*)&g2s[(size_t)node * HID + col * 4] = pk;
    }
}

// MFMA GEMM: h2 = relu(g2s @ W2 + b2); part[block] = sum_rows h2 . Wf
__global__ __launch_bounds__(256) void k_gemm2m(const unsigned short* __restrict__ g2s,
                                                const unsigned short* __restrict__ W2T,
                                                const float* __restrict__ b2,
                                                const float* __restrict__ Wf,
                                                float* __restrict__ part, int n) {
    __shared__ unsigned short ldsB[HID][HID + 8];   // 34.8KB
    __shared__ float sbp[4];
    int tid = threadIdx.x;
    int wv = tid >> 6;
    int lane = tid & 63;

    #pragma unroll
    for (int q = 0; q < 8; ++q) {
        int id = tid + q * 256;
        int row = id >> 4, ch = id & 15;
        *(uint4*)&ldsB[row][ch * 8] = *(const uint4*)&W2T[(size_t)row * HID + ch * 8];
    }
    __syncthreads();

    int r0 = blockIdx.x * 64 + wv * 16;
    int arow = r0 + (lane & 15);
    int koff = (lane >> 4) * 8;

    bf16x8 af[4];
    #pragma unroll
    for (int kk = 0; kk < 4; ++kk)
        af[kk] = *(const bf16x8*)&g2s[(size_t)arow * HID + kk * 32 + koff];

    f32x4 acc[8];
    #pragma unroll
    for (int ct = 0; ct < 8; ++ct) acc[ct] = (f32x4){0.f, 0.f, 0.f, 0.f};

    #pragma unroll
    for (int kk = 0; kk < 4; ++kk) {
        #pragma unroll
        for (int ct = 0; ct < 8; ++ct) {
            bf16x8 bfr = *(const bf16x8*)&ldsB[ct * 16 + (lane & 15)][kk * 32 + koff];
            acc[ct] = __builtin_amdgcn_mfma_f32_16x16x32_bf16(af[kk], bfr, acc[ct], 0, 0, 0);
        }
    }

    float d = 0.f;
    #pragma unroll
    for (int ct = 0; ct < 8; ++ct) {
        int col = ct * 16 + (lane & 15);
        float b2v = b2[col];
        float wfv = Wf[col];
        #pragma unroll
        for (int q = 0; q < 4; ++q) {
            int row = r0 + (lane >> 4) * 4 + q;
            if (row < n) {
                float h = fmaxf(acc[ct][q] + b2v, 0.f);
                d += h * wfv;
            }
        }
    }
    #pragma unroll
    for (int o = 32; o > 0; o >>= 1) d += __shfl_down(d, o);
    if (lane == 0) sbp[wv] = d;
    __syncthreads();
    if (tid == 0) part[blockIdx.x] = sbp[0] + sbp[1] + sbp[2] + sbp[3];
}

// reduce block partials + bias
__global__ void k_final2(const float* __restrict__ part, int npart,
                         const float* __restrict__ bf, float* __restrict__ out,
                         float invn) {
    __shared__ float sb[256];
    float s = 0.f;
    for (int i = threadIdx.x; i < npart; i += 256) s += part[i];
    sb[threadIdx.x] = s;
    __syncthreads();
    for (int o = 128; o > 0; o >>= 1) {
        if (threadIdx.x < o) sb[threadIdx.x] += sb[threadIdx.x + o];
        __syncthreads();
    }
    if (threadIdx.x == 0) out[0] = sb[0] * invn + bf[0];
}

extern "C" void kernel_launch(void* const* d_in, const int* in_sizes, int n_in,
                              void* d_out, int out_size, void* d_ws, size_t ws_size,
                              hipStream_t stream) {
    const float* x  = (const float*)d_in[0];
    const int*   ei = (const int*)d_in[1];
    const float* W1 = (const float*)d_in[2];
    const float* b1 = (const float*)d_in[3];
    const float* W2 = (const float*)d_in[4];
    const float* b2 = (const float*)d_in[5];
    const float* Wf = (const float*)d_in[6];
    const float* bf = (const float*)d_in[7];
    int n = in_sizes[0] / 3;
    int E = in_sizes[1] / 2;
    const int* src = ei;
    const int* dst = ei + E;
    int nper = ((n + NWIN - 1) / NWIN + 63) & ~63;
    int npart = (n + 63) / 64;

    char* w = (char*)d_ws;
    int*    deg    = (int*)(w + 0);                    // 400KB
    int*    off    = (int*)(w + (512ll << 10));        // 400KB
    int*    cursor = (int*)(w + (1024ll << 10));       // 400KB
    float*  dinv   = (float*)(w + (1536ll << 10));     // 400KB
    int*    wintot = (int*)(w + (2048ll << 10) + 128); // 32B
    int*    wincur = (int*)(w + (2048ll << 10) + 256); // 32B
    int*    csr    = (int*)(w + (2560ll << 10));       // 6.4MB
    float4* xs     = (float4*)(w + (9ll << 20));       // 1.6MB
    float4* agg1   = (float4*)(w + (11ll << 20));      // 1.6MB
    unsigned short* h1s = (unsigned short*)(w + (13ll << 20)); // 25.6MB
    unsigned short* g2s = (unsigned short*)(w + (39ll << 20)); // 25.6MB
    unsigned short* W2T = (unsigned short*)(w + (66ll << 20)); // 32KB
    float*  part   = (float*)(w + (67ll << 20));       // 6.3KB

    hipMemsetAsync(deg, 0, (size_t)n * sizeof(int), stream);
    hipMemsetAsync(wintot, 0, 256, stream);

    k_w2t<<<(HID * HID + 255) / 256, 256, 0, stream>>>(W2, W2T);
    k_deg<<<1024, 256, 0, stream>>>(dst, deg, wintot, E, nper);
    k_winscan<<<1, 64, 0, stream>>>(wintot, wincur);
    k_off<<<(n + 255) / 256, 256, 0, stream>>>(deg, x, off, cursor, dinv, xs, wincur, n, nper);
    k_fill<<<1024, 256, 0, stream>>>(src, dst, cursor, csr, E, nper);

    k_agg1<<<(n + 255) / 256, 256, 0, stream>>>(xs, off, deg, csr, agg1, n);
    k_h1<<<(n + 3) / 4, 256, 0, stream>>>(agg1, W1, b1, h1s, n);
    k_agg2<<<(n + 3) / 4, 256, 0, stream>>>(h1s, dinv, off, deg, csr, g2s, n);
    k_gemm2m<<<npart, 256, 0, stream>>>(g2s, W2T, b2, Wf, part, n);
    k_final2<<<1, 256, 0, stream>>>(part, npart, bf, (float*)d_out, 1.0f / (float)n);
}

// Round 17
// 243.443 us; speedup vs baseline: 1.4800x; 1.4800x over previous
//
#include <hip/hip_runtime.h>
#include <hip/hip_bf16.h>
#include <cstdint>
#include <cstddef>

// GCN restructured:
//   conv1: agg RAW 3-dim features, W1 AFTER agg.  conv2: agg bf16 h1s rows -> bf16 g2s,
//   then MFMA bf16 GEMM (g2s @ W2) with relu+Wf+pool fused; block partials + LDS-staged W2T.
// CSR build: LDS counting sort (hist -> scan -> scatter -> per-bucket CSR).
//   ZERO per-edge global atomics: device-scope atomics execute memory-side on gfx950
//   (~32B HBM write each; E=1.6M of them was 50-70MB of write traffic in deg/fill).

#define HID 128
#define MAXBUK 512          // buckets of 256 nodes; n<=131072
#define NBLK_BIN 256        // blocks in hist/scatter passes

typedef short bf16x8 __attribute__((ext_vector_type(8)));
typedef float f32x4 __attribute__((ext_vector_type(4)));

__device__ inline float bflo(unsigned u) { return __uint_as_float(u << 16); }
__device__ inline float bfhi(unsigned u) { return __uint_as_float(u & 0xffff0000u); }
__device__ inline unsigned short f2bf(float f) {
    __hip_bfloat16 q = __float2bfloat16(f);
    return *(unsigned short*)&q;
}

// W2T[c][k] = bf16(W2[k][c])
__global__ void k_w2t(const float* __restrict__ W2, unsigned short* __restrict__ W2T) {
    int i = blockIdx.x * 256 + threadIdx.x;
    if (i < HID * HID) {
        int k = i >> 7, c = i & 127;
        W2T[c * HID + k] = f2bf(W2[k * HID + c]);
    }
}

// pass 1: per-block LDS histogram over dst buckets (bucket = dst>>8)
__global__ __launch_bounds__(256) void k_hist(const int* __restrict__ dst,
                                              int* __restrict__ counts,
                                              int E, int chunk, int nbuk) {
    __shared__ int h[MAXBUK];
    for (int i = threadIdx.x; i < MAXBUK; i += 256) h[i] = 0;
    __syncthreads();
    int lo = blockIdx.x * chunk;
    int hi = lo + chunk; if (hi > E) hi = E;
    for (int e = lo + threadIdx.x; e < hi; e += 256)
        atomicAdd(&h[dst[e] >> 8], 1);            // LDS atomic
    __syncthreads();
    for (int i = threadIdx.x; i < nbuk; i += 256)
        counts[blockIdx.x * nbuk + i] = h[i];     // normal store
}

// pass 2: single block; bucket starts + per-(block,bucket) scatter offsets
__global__ __launch_bounds__(512) void k_scan2(const int* __restrict__ counts,
                                               int* __restrict__ off_mat,
                                               int* __restrict__ bstart,
                                               int nbuk, int E) {
    __shared__ int tot[MAXBUK];
    int t = threadIdx.x;
    int s = 0;
    if (t < nbuk)
        for (int b = 0; b < NBLK_BIN; ++b) s += counts[b * nbuk + t];
    tot[t] = s;
    __syncthreads();
    for (int o = 1; o < MAXBUK; o <<= 1) {
        int v = (t >= o) ? tot[t - o] : 0;
        __syncthreads();
        tot[t] += v;
        __syncthreads();
    }
    int start = tot[t] - s;                        // exclusive
    if (t < nbuk) {
        bstart[t] = start;
        int run = start;
        for (int b = 0; b < NBLK_BIN; ++b) {
            off_mat[b * nbuk + t] = run;
            run += counts[b * nbuk + t];
        }
    }
    if (t == 0) bstart[nbuk] = E;
}

// pass 3: scatter edges into bucket-binned (src,dst) array; LDS cursors, normal stores
__global__ __launch_bounds__(256) void k_scatter(const int* __restrict__ src,
                                                 const int* __restrict__ dst,
                                                 const int* __restrict__ off_mat,
                                                 int2* __restrict__ binned,
                                                 int E, int chunk, int nbuk) {
    __shared__ int cur[MAXBUK];
    for (int i = threadIdx.x; i < nbuk; i += 256)
        cur[i] = off_mat[blockIdx.x * nbuk + i];
    __syncthreads();
    int lo = blockIdx.x * chunk;
    int hi = lo + chunk; if (hi > E) hi = E;
    for (int e = lo + threadIdx.x; e < hi; e += 256) {
        int d = dst[e];
        int p = atomicAdd(&cur[d >> 8], 1);        // LDS atomic
        binned[p] = make_int2(src[e], d);          // normal store
    }
}

// pass 4: one block per bucket (256 nodes); LDS hist+scan -> deg/off/dinv/xs + csr fill
__global__ __launch_bounds__(256) void k_csr(const int2* __restrict__ binned,
                                             const int* __restrict__ bstart,
                                             const float* __restrict__ x,
                                             int* __restrict__ csr, int* __restrict__ off,
                                             int* __restrict__ deg, float* __restrict__ dinv,
                                             float4* __restrict__ xs, int n) {
    __shared__ int sc[256];
    __shared__ int cur[256];
    int t = threadIdx.x;
    int b = blockIdx.x;
    int nlo = b << 8;
    int elo = bstart[b], ehi = bstart[b + 1];
    sc[t] = 0;
    __syncthreads();
    for (int e = elo + t; e < ehi; e += 256)
        atomicAdd(&sc[binned[e].y & 255], 1);      // LDS atomic
    __syncthreads();
    int dg = sc[t];
    // inclusive scan over 256
    for (int o = 1; o < 256; o <<= 1) {
        int v = (t >= o) ? sc[t - o] : 0;
        __syncthreads();
        sc[t] += v;
        __syncthreads();
    }
    int base = elo + sc[t] - dg;                   // global exclusive offset
    cur[t] = base;
    int i = nlo + t;
    if (i < n) {
        deg[i] = dg;
        off[i] = base;
        float di = rsqrtf((float)(dg + 1));
        dinv[i] = di;
        xs[i] = make_float4(x[3 * i] * di, x[3 * i + 1] * di, x[3 * i + 2] * di, di);
    }
    __syncthreads();
    for (int e = elo + t; e < ehi; e += 256) {
        int2 ed = binned[e];
        int p = atomicAdd(&cur[ed.y & 255], 1);    // LDS atomic
        csr[p] = ed.x;                             // normal store, bucket-local region
    }
}

// conv1 aggregation on 3-dim raw features: one THREAD per node, 4x unrolled.
__global__ void k_agg1(const float4* __restrict__ xs, const int* __restrict__ off,
                       const int* __restrict__ deg, const int* __restrict__ csr,
                       float4* __restrict__ agg1, int n) {
    int i = blockIdx.x * 256 + threadIdx.x;
    if (i >= n) return;
    int e0 = off[i], e1 = e0 + deg[i];
    float sx = 0.f, sy = 0.f, sz = 0.f;
    int e = e0;
    for (; e + 4 <= e1; e += 4) {
        int s0 = csr[e], s1 = csr[e + 1], s2 = csr[e + 2], s3 = csr[e + 3];
        float4 v0 = xs[s0], v1 = xs[s1], v2 = xs[s2], v3 = xs[s3];
        sx += v0.x + v1.x + v2.x + v3.x;
        sy += v0.y + v1.y + v2.y + v3.y;
        sz += v0.z + v1.z + v2.z + v3.z;
    }
    for (; e < e1; ++e) {
        float4 v = xs[csr[e]];
        sx += v.x; sy += v.y; sz += v.z;
    }
    float4 self = xs[i];
    float di = self.w;
    agg1[i] = make_float4((sx + self.x) * di, (sy + self.y) * di, (sz + self.z) * di, di);
}

// h1s[i] = bf16( relu(agg1[i].xyz @ W1 + b1) * dinv )
__global__ __launch_bounds__(256) void k_h1(const float4* __restrict__ agg1,
                                            const float* __restrict__ W1,
                                            const float* __restrict__ b1,
                                            unsigned short* __restrict__ h1s, int n) {
    int wv = threadIdx.x >> 6;
    int lane = threadIdx.x & 63;
    int i = blockIdx.x * 4 + wv;
    if (i >= n) return;
    int c0 = lane * 2;
    float4 a = agg1[i];
    float h0 = fmaxf(a.x * W1[0 * HID + c0]     + a.y * W1[1 * HID + c0]     + a.z * W1[2 * HID + c0]     + b1[c0],     0.f) * a.w;
    float h1 = fmaxf(a.x * W1[0 * HID + c0 + 1] + a.y * W1[1 * HID + c0 + 1] + a.z * W1[2 * HID + c0 + 1] + b1[c0 + 1], 0.f) * a.w;
    ushort2 pk;
    pk.x = f2bf(h0);
    pk.y = f2bf(h1);
    *(ushort2*)&h1s[(size_t)i * HID + c0] = pk;
}

// conv2 aggregation over bf16 rows; OUTPUT bf16 g2s.
__global__ __launch_bounds__(256) void k_agg2(const unsigned short* __restrict__ h1s,
                                              const float* __restrict__ dinv,
                                              const int* __restrict__ off,
                                              const int* __restrict__ deg,
                                              const int* __restrict__ csr,
                                              unsigned short* __restrict__ g2s, int n) {
    int wv = threadIdx.x >> 6;
    int lane = threadIdx.x & 63;
    int half = lane >> 5;
    int col = lane & 31;
    int node = blockIdx.x * 4 + wv;
    if (node >= n) return;
    int e0 = off[node], e1 = e0 + deg[node];
    float ax = 0.f, ay = 0.f, az = 0.f, aw = 0.f;

    for (int base = e0; base < e1; base += 64) {
        int m = e1 - base; if (m > 64) m = 64;
        int idx = (base + lane < e1) ? csr[base + lane] : 0;
        int j = 0;
        for (; j + 8 <= m; j += 8) {
            int s0 = __shfl(idx, j + 0 + half);
            int s1 = __shfl(idx, j + 2 + half);
            int s2 = __shfl(idx, j + 4 + half);
            int s3 = __shfl(idx, j + 6 + half);
            uint2 r0 = *(const uint2*)&h1s[(size_t)s0 * HID + col * 4];
            uint2 r1 = *(const uint2*)&h1s[(size_t)s1 * HID + col * 4];
            uint2 r2 = *(const uint2*)&h1s[(size_t)s2 * HID + col * 4];
            uint2 r3 = *(const uint2*)&h1s[(size_t)s3 * HID + col * 4];
            ax += bflo(r0.x) + bflo(r1.x) + bflo(r2.x) + bflo(r3.x);
            ay += bfhi(r0.x) + bfhi(r1.x) + bfhi(r2.x) + bfhi(r3.x);
            az += bflo(r0.y) + bflo(r1.y) + bflo(r2.y) + bflo(r3.y);
            aw += bfhi(r0.y) + bfhi(r1.y) + bfhi(r2.y) + bfhi(r3.y);
        }
        for (; j < m; j += 2) {
            int jj = j + half;
            if (jj < m) {
                int s = __shfl(idx, jj);
                uint2 r = *(const uint2*)&h1s[(size_t)s * HID + col * 4];
                ax += bflo(r.x); ay += bfhi(r.x);
                az += bflo(r.y); aw += bfhi(r.y);
            }
        }
    }
    ax += __shfl_down(ax, 32);
    ay += __shfl_down(ay, 32);
    az += __shfl_down(az, 32);
    aw += __shfl_down(aw, 32);

    if (half == 0) {
        uint2 r = *(const uint2*)&h1s[(size_t)node * HID + col * 4];
        float di = dinv[node];
        ushort4 pk;
        pk.x = f2bf((ax + bflo(r.x)) * di);
        pk.y = f2bf((ay + bfhi(r.x)) * di);
        pk.z = f2bf((az + bflo(r.y)) * di);
        pk.w = f2bf((aw + bfhi(r.y)) * di);
        *(ushort4*)&g2s[(size_t)node * HID + col * 4] = pk;
    }
}

// MFMA GEMM: h2 = relu(g2s @ W2 + b2); part[block] = sum_rows h2 . Wf
__global__ __launch_bounds__(256) void k_gemm2m(const unsigned short* __restrict__ g2s,
                                                const unsigned short* __restrict__ W2T,
                                                const float* __restrict__ b2,
                                                const float* __restrict__ Wf,
                                                float* __restrict__ part, int n) {
    __shared__ unsigned short ldsB[HID][HID + 8];
    __shared__ float sbp[4];
    int tid = threadIdx.x;
    int wv = tid >> 6;
    int lane = tid & 63;

    #pragma unroll
    for (int q = 0; q < 8; ++q) {
        int id = tid + q * 256;
        int row = id >> 4, ch = id & 15;
        *(uint4*)&ldsB[row][ch * 8] = *(const uint4*)&W2T[(size_t)row * HID + ch * 8];
    }
    __syncthreads();

    int r0 = blockIdx.x * 64 + wv * 16;
    int arow = r0 + (lane & 15);
    int koff = (lane >> 4) * 8;

    bf16x8 af[4];
    #pragma unroll
    for (int kk = 0; kk < 4; ++kk)
        af[kk] = *(const bf16x8*)&g2s[(size_t)arow * HID + kk * 32 + koff];

    f32x4 acc[8];
    #pragma unroll
    for (int ct = 0; ct < 8; ++ct) acc[ct] = (f32x4){0.f, 0.f, 0.f, 0.f};

    #pragma unroll
    for (int kk = 0; kk < 4; ++kk) {
        #pragma unroll
        for (int ct = 0; ct < 8; ++ct) {
            bf16x8 bfr = *(const bf16x8*)&ldsB[ct * 16 + (lane & 15)][kk * 32 + koff];
            acc[ct] = __builtin_amdgcn_mfma_f32_16x16x32_bf16(af[kk], bfr, acc[ct], 0, 0, 0);
        }
    }

    float d = 0.f;
    #pragma unroll
    for (int ct = 0; ct < 8; ++ct) {
        int col = ct * 16 + (lane & 15);
        float b2v = b2[col];
        float wfv = Wf[col];
        #pragma unroll
        for (int q = 0; q < 4; ++q) {
            int row = r0 + (lane >> 4) * 4 + q;
            if (row < n) {
                float h = fmaxf(acc[ct][q] + b2v, 0.f);
                d += h * wfv;
            }
        }
    }
    #pragma unroll
    for (int o = 32; o > 0; o >>= 1) d += __shfl_down(d, o);
    if (lane == 0) sbp[wv] = d;
    __syncthreads();
    if (tid == 0) part[blockIdx.x] = sbp[0] + sbp[1] + sbp[2] + sbp[3];
}

// reduce block partials + bias
__global__ void k_final2(const float* __restrict__ part, int npart,
                         const float* __restrict__ bf, float* __restrict__ out,
                         float invn) {
    __shared__ float sb[256];
    float s = 0.f;
    for (int i = threadIdx.x; i < npart; i += 256) s += part[i];
    sb[threadIdx.x] = s;
    __syncthreads();
    for (int o = 128; o > 0; o >>= 1) {
        if (threadIdx.x < o) sb[threadIdx.x] += sb[threadIdx.x + o];
        __syncthreads();
    }
    if (threadIdx.x == 0) out[0] = sb[0] * invn + bf[0];
}

extern "C" void kernel_launch(void* const* d_in, const int* in_sizes, int n_in,
                              void* d_out, int out_size, void* d_ws, size_t ws_size,
                              hipStream_t stream) {
    const float* x  = (const float*)d_in[0];
    const int*   ei = (const int*)d_in[1];
    const float* W1 = (const float*)d_in[2];
    const float* b1 = (const float*)d_in[3];
    const float* W2 = (const float*)d_in[4];
    const float* b2 = (const float*)d_in[5];
    const float* Wf = (const float*)d_in[6];
    const float* bf = (const float*)d_in[7];
    int n = in_sizes[0] / 3;
    int E = in_sizes[1] / 2;
    const int* src = ei;
    const int* dst = ei + E;
    int nbuk = (n + 255) >> 8;                      // <= MAXBUK
    int chunk = (E + NBLK_BIN - 1) / NBLK_BIN;
    int npart = (n + 63) / 64;

    char* w = (char*)d_ws;
    int*    deg     = (int*)(w + 0);                    // 400KB
    int*    off     = (int*)(w + (512ll << 10));        // 400KB
    float*  dinv    = (float*)(w + (1024ll << 10));     // 400KB
    float4* xs      = (float4*)(w + (1536ll << 10));    // 1.6MB -> ends 3.1MB
    float4* agg1    = (float4*)(w + (3584ll << 10));    // 1.6MB -> ends 5.1MB
    int*    counts  = (int*)(w + (5632ll << 10));       // 512KB
    int*    off_mat = (int*)(w + (6144ll << 10));       // 512KB
    int*    bstart  = (int*)(w + (6656ll << 10));       // 4KB
    float*  part    = (float*)(w + (6784ll << 10));     // 8KB
    unsigned short* W2T = (unsigned short*)(w + (6912ll << 10)); // 32KB
    int*    csr     = (int*)(w + (7ll << 20));          // 6.4MB -> ends 13.4MB
    int2*   binned  = (int2*)(w + (14ll << 20));        // 12.8MB -> ends 26.8MB
    unsigned short* h1s = (unsigned short*)(w + (27ll << 20)); // 25.6MB -> ends 52.6MB
    unsigned short* g2s = (unsigned short*)(w + (53ll << 20)); // 25.6MB -> ends 78.6MB

    k_w2t<<<(HID * HID + 255) / 256, 256, 0, stream>>>(W2, W2T);
    k_hist<<<NBLK_BIN, 256, 0, stream>>>(dst, counts, E, chunk, nbuk);
    k_scan2<<<1, 512, 0, stream>>>(counts, off_mat, bstart, nbuk, E);
    k_scatter<<<NBLK_BIN, 256, 0, stream>>>(src, dst, off_mat, binned, E, chunk, nbuk);
    k_csr<<<nbuk, 256, 0, stream>>>(binned, bstart, x, csr, off, deg, dinv, xs, n);

    k_agg1<<<(n + 255) / 256, 256, 0, stream>>>(xs, off, deg, csr, agg1, n);
    k_h1<<<(n + 3) / 4, 256, 0, stream>>>(agg1, W1, b1, h1s, n);
    k_agg2<<<(n + 3) / 4, 256, 0, stream>>>(h1s, dinv, off, deg, csr, g2s, n);
    k_gemm2m<<<npart, 256, 0, stream>>>(g2s, W2T, b2, Wf, part, n);
    k_final2<<<1, 256, 0, stream>>>(part, npart, bf, (float*)d_out, 1.0f / (float)n);
}